// Round 9
// baseline (46.546 us; speedup 1.0000x reference)
//
#include <hip/hip_runtime.h>

// BertWordEmbedder: B=64, T=512, H=768, W=256, D=256
//   prep:        [0..191] proj_w -> wt [256][768] bf16 ; [192..255] bounds
//   pool_pair:   one WAVE per WORD PAIR; R9: __launch_bounds__(256,8)
//                (<=64 VGPR -> 32 waves/CU) + unroll-2 (6 loads in flight).
//                Tests the occupancy hypothesis for pool's BW gap.
//   gemm_lds:    R6-proven LDS-staged MFMA GEMM; R9: XCD-chunked block swizzle
//                (4 col-tiles of one A-panel co-located per XCD L2).
// ws: [0) wt 393216 | [393216) bounds 65792 | [524288) we 25165824

#define NB 64
#define NT 512
#define NH 768
#define NW 256
#define ND 256

typedef __attribute__((ext_vector_type(8))) short short8;
typedef __attribute__((ext_vector_type(4))) float f32x4;
typedef __attribute__((ext_vector_type(4))) float float4v;
typedef __attribute__((ext_vector_type(4))) unsigned int uint4v;
typedef __attribute__((ext_vector_type(4))) unsigned short ushort4v;

__device__ __forceinline__ unsigned short f2bf(float f) {
    union { float f; unsigned u; } v; v.f = f;
    unsigned r = v.u + 0x7fffu + ((v.u >> 16) & 1u);  // RNE
    return (unsigned short)(r >> 16);
}

// merged prep: wt transpose (192 blocks) + bounds (64 blocks)
__global__ void prep(const float* __restrict__ w, const int* __restrict__ wid,
                     unsigned short* __restrict__ wt, int* __restrict__ bounds) {
    __shared__ float tile[32][33];
    __shared__ int s[NT];
    const int tid = threadIdx.x, n = blockIdx.x;
    if (n < 192) {
        int tx = tid & 31, ty = tid >> 5;
        int k0 = (n % 24) * 32, n0 = (n / 24) * 32;
        #pragma unroll
        for (int i = 0; i < 4; ++i)
            tile[ty + 8 * i][tx] = w[(size_t)(k0 + ty + 8 * i) * ND + n0 + tx];
        __syncthreads();
        #pragma unroll
        for (int i = 0; i < 4; ++i)
            wt[(size_t)(n0 + ty + 8 * i) * NH + k0 + tx] = f2bf(tile[tx][ty + 8 * i]);
    } else {
        int b = n - 192;
        s[tid]       = wid[b * NT + tid];
        s[tid + 256] = wid[b * NT + tid + 256];
        __syncthreads();
        for (int w2 = tid; w2 <= NW; w2 += 256) {
            int lo = 0, hi = NT;
            while (lo < hi) { int m = (lo + hi) >> 1; if (s[m] < w2) lo = m + 1; else hi = m; }
            bounds[b * (NW + 1) + w2] = lo;
        }
    }
}

// one wave per word PAIR: contiguous token range [s,e), boundary m splits it.
// unroll-2 (6 loads in flight) + forced 8 waves/EU occupancy.
__global__ __launch_bounds__(256, 8)
void pool_pair(const float* __restrict__ hs, const int* __restrict__ bounds,
               unsigned short* __restrict__ we) {
    const int wave = threadIdx.x >> 6, lane = threadIdx.x & 63;
    const int idx = blockIdx.x * 4 + wave;          // 0..8191 = (b, wordpair j)
    const int b = idx >> 7, j = idx & 127;

    const int* bp = bounds + b * (NW + 1) + 2 * j;
    int s = __builtin_amdgcn_readfirstlane(bp[0]);
    int m = __builtin_amdgcn_readfirstlane(bp[1]);
    int e = __builtin_amdgcn_readfirstlane(bp[2]);

    const float* base = hs + (size_t)b * NT * NH + lane * 4;
    float4v a0c0 = {0,0,0,0}, a0c1 = {0,0,0,0}, a0c2 = {0,0,0,0};
    float4v a1c0 = {0,0,0,0}, a1c1 = {0,0,0,0}, a1c2 = {0,0,0,0};

#define ROUTE(t, v0, v1, v2) {                                                \
        if ((t) < m) {                                                        \
            _Pragma("unroll") for (int q = 0; q < 4; ++q) {                   \
                a0c0[q] += (v0)[q]; a0c1[q] += (v1)[q]; a0c2[q] += (v2)[q]; } \
        } else {                                                              \
            _Pragma("unroll") for (int q = 0; q < 4; ++q) {                   \
                a1c0[q] += (v0)[q]; a1c1[q] += (v1)[q]; a1c2[q] += (v2)[q]; } \
        }                                                                     \
    }

    int t = s;
    for (; t + 2 <= e; t += 2) {                    // 6 loads in flight
        float4v v[2][3];
        #pragma unroll
        for (int u = 0; u < 2; ++u) {
            const float* p = base + (size_t)(t + u) * NH;
            v[u][0] = *(const float4v*)(p);
            v[u][1] = *(const float4v*)(p + 256);
            v[u][2] = *(const float4v*)(p + 512);
        }
        #pragma unroll
        for (int u = 0; u < 2; ++u) ROUTE(t + u, v[u][0], v[u][1], v[u][2]);
    }
    if (t < e) {
        const float* p = base + (size_t)t * NH;
        float4v v0 = *(const float4v*)(p);
        float4v v1 = *(const float4v*)(p + 256);
        float4v v2 = *(const float4v*)(p + 512);
        ROUTE(t, v0, v1, v2);
    }
#undef ROUTE

    int c0 = m - s; if (c0 < 1) c0 = 1;
    int c1 = e - m; if (c1 < 1) c1 = 1;
    const float s0 = 1.0f / (float)c0, s1 = 1.0f / (float)c1;

    unsigned short* d0 = we + (size_t)(2 * idx) * NH + lane * 4;
    unsigned short* d1 = d0 + NH;
    ushort4v u;
    #pragma unroll
    for (int q = 0; q < 4; ++q) u[q] = f2bf(a0c0[q] * s0);
    *(ushort4v*)(d0) = u;
    #pragma unroll
    for (int q = 0; q < 4; ++q) u[q] = f2bf(a0c1[q] * s0);
    *(ushort4v*)(d0 + 256) = u;
    #pragma unroll
    for (int q = 0; q < 4; ++q) u[q] = f2bf(a0c2[q] * s0);
    *(ushort4v*)(d0 + 512) = u;
    #pragma unroll
    for (int q = 0; q < 4; ++q) u[q] = f2bf(a1c0[q] * s1);
    *(ushort4v*)(d1) = u;
    #pragma unroll
    for (int q = 0; q < 4; ++q) u[q] = f2bf(a1c1[q] * s1);
    *(ushort4v*)(d1 + 256) = u;
    #pragma unroll
    for (int q = 0; q < 4; ++q) u[q] = f2bf(a1c2[q] * s1);
    *(ushort4v*)(d1 + 512) = u;
}

// out[16384x256] = we @ wt^T + bias. R6-proven loop; XCD-chunked swizzle:
// 4 consecutive swz = 4 col-tiles of one row-panel -> same XCD L2.
__global__ __launch_bounds__(256)
void gemm_lds(const unsigned short* __restrict__ we, const unsigned short* __restrict__ wt,
              const float* __restrict__ bias, float* __restrict__ out) {
    __shared__ unsigned short Asm[128][72];
    __shared__ unsigned short Bsm[64][72];

    const int tid = threadIdx.x, wave = tid >> 6, lane = tid & 63;
    const int cl = lane & 15, kg = lane >> 4;
    const int bid = blockIdx.x;                     // 0..511
    const int swz = (bid & 7) * 64 + (bid >> 3);    // bijective (512 % 8 == 0)
    const size_t r0 = (size_t)(swz >> 2) * 128;
    const int c0 = (swz & 3) * 64;
    const int wm0 = (wave >> 1) * 64, wn0 = (wave & 1) * 32;

    const int arow = tid >> 1, ah = tid & 1;
    const int brow = tid >> 2, bq = tid & 3;
    const unsigned short* agp = we + (r0 + arow) * NH;
    const unsigned short* bgp = wt + (size_t)(c0 + brow) * NH;

    uint4v sA0[4], sB0[2], sA1[4], sB1[2];

    auto gload = [&](uint4v* sA, uint4v* sB, int k0e) {
        #pragma unroll
        for (int i = 0; i < 4; ++i)
            sA[i] = *(const uint4v*)(agp + k0e + (ah + 2 * i) * 8);
        #pragma unroll
        for (int i = 0; i < 2; ++i)
            sB[i] = *(const uint4v*)(bgp + k0e + (bq + 4 * i) * 8);
    };
    auto swrite = [&](uint4v* sA, uint4v* sB) {
        #pragma unroll
        for (int i = 0; i < 4; ++i)
            *(uint4v*)&Asm[arow][(ah + 2 * i) * 8] = sA[i];
        #pragma unroll
        for (int i = 0; i < 2; ++i)
            *(uint4v*)&Bsm[brow][(bq + 4 * i) * 8] = sB[i];
    };

    f32x4 acc[4][2];
    #pragma unroll
    for (int mt = 0; mt < 4; ++mt)
        #pragma unroll
        for (int nt = 0; nt < 2; ++nt)
            #pragma unroll
            for (int r = 0; r < 4; ++r) acc[mt][nt][r] = 0.f;

    auto compute = [&]() {
        short8 af[4][2], bf[2][2];
        #pragma unroll
        for (int mt = 0; mt < 4; ++mt)
            #pragma unroll
            for (int km = 0; km < 2; ++km)
                af[mt][km] = *(const short8*)&Asm[wm0 + mt * 16 + cl][km * 32 + kg * 8];
        #pragma unroll
        for (int nt = 0; nt < 2; ++nt)
            #pragma unroll
            for (int km = 0; km < 2; ++km)
                bf[nt][km] = *(const short8*)&Bsm[wn0 + nt * 16 + cl][km * 32 + kg * 8];
        #pragma unroll
        for (int mt = 0; mt < 4; ++mt)
            #pragma unroll
            for (int nt = 0; nt < 2; ++nt)
                #pragma unroll
                for (int km = 0; km < 2; ++km)
                    acc[mt][nt] = __builtin_amdgcn_mfma_f32_16x16x32_bf16(af[mt][km], bf[nt][km], acc[mt][nt], 0, 0, 0);
    };

    gload(sA0, sB0, 0);
    for (int ks = 0; ks < 12; ks += 2) {
        swrite(sA0, sB0);
        __syncthreads();
        gload(sA1, sB1, (ks + 1) * 64);
        compute();
        __syncthreads();
        swrite(sA1, sB1);
        __syncthreads();
        if (ks + 2 < 12) gload(sA0, sB0, (ks + 2) * 64);
        compute();
        __syncthreads();
    }

    float bv[2];
    bv[0] = bias[c0 + wn0 + cl];
    bv[1] = bias[c0 + wn0 + 16 + cl];

    #pragma unroll
    for (int mt = 0; mt < 4; ++mt)
        #pragma unroll
        for (int nt = 0; nt < 2; ++nt)
            #pragma unroll
            for (int r = 0; r < 4; ++r)
                out[(r0 + wm0 + mt * 16 + kg * 4 + r) * ND + c0 + wn0 + nt * 16 + cl]
                    = acc[mt][nt][r] + bv[nt];
}

extern "C" void kernel_launch(void* const* d_in, const int* in_sizes, int n_in,
                              void* d_out, int out_size, void* d_ws, size_t ws_size,
                              hipStream_t stream) {
    const float* hs  = (const float*)d_in[0];
    const int*   wid = (const int*)d_in[1];
    const float* pw  = (const float*)d_in[2];
    const float* pb  = (const float*)d_in[3];
    float* out = (float*)d_out;

    unsigned short* wt = (unsigned short*)d_ws;                      // 393216 B
    int* bounds        = (int*)((char*)d_ws + 393216);               // 65792 B
    unsigned short* we = (unsigned short*)((char*)d_ws + 524288);    // 25165824 B

    prep<<<256, 256, 0, stream>>>(pw, wid, wt, bounds);
    pool_pair<<<(NB * NW / 2) / 4, 256, 0, stream>>>(hs, bounds, we);
    gemm_lds<<<NB * NW / 128 * (ND / 64), 256, 0, stream>>>(we, wt, pb, out);
}